// Round 1
// baseline (905.729 us; speedup 1.0000x reference)
//
#include <hip/hip_runtime.h>

#define BATCH 65536
#define HID   512
#define NCLS  1000
#define NCLSP 1024

typedef short bf16x8 __attribute__((ext_vector_type(8)));
typedef float f32x4 __attribute__((ext_vector_type(4)));
typedef unsigned short u16;
typedef unsigned int u32;

__device__ __forceinline__ u16 f2bf(float f) {
  u32 u = __float_as_uint(f);
  u += 0x7fffu + ((u >> 16) & 1u);
  return (u16)(u >> 16);
}

// ---------------- ws layout ----------------
// counts  int[1024]         @ 0
// accum   double[8]         @ 4096   (0 stab, 1 center, 2 sep, 3 brier)
// sq      float[1024]       @ 8192
// sums    float[1024*512]   @ 16384
// centers float[1024*512]   @ 2113536
// WbFrag  u16[16*1024*32]   @ 4210688   (frag-linear bf16 W)
#define WS_END 5259264

// ---------------- counts + segment sums ----------------
__global__ void k_count_sum(const float* __restrict__ cls, const int* __restrict__ labels,
                            float* __restrict__ sums, int* __restrict__ counts) {
  const int lane = threadIdx.x & 63;
  const int wid  = (blockIdx.x * blockDim.x + threadIdx.x) >> 6;
  const int nw   = (gridDim.x * blockDim.x) >> 6;
  for (int row = wid; row < BATCH; row += nw) {
    const int lab = labels[row];
    const float4* src = (const float4*)(cls + (size_t)row * HID);
    float4 a = src[lane];
    float4 b = src[lane + 64];
    float* dst = sums + (size_t)lab * HID;
    const int o = lane * 4;
    atomicAdd(dst + o + 0, a.x);
    atomicAdd(dst + o + 1, a.y);
    atomicAdd(dst + o + 2, a.z);
    atomicAdd(dst + o + 3, a.w);
    atomicAdd(dst + 256 + o + 0, b.x);
    atomicAdd(dst + 256 + o + 1, b.y);
    atomicAdd(dst + 256 + o + 2, b.z);
    atomicAdd(dst + 256 + o + 3, b.w);
    if (lane == 0) atomicAdd(counts + lab, 1);
  }
}

// ---------------- W f32 -> fragment-linear bf16 ----------------
// WbFrag[((kc*1024 + col)*4 + kg)*8 + i] = W[kc*32 + kg*8 + i][col], 0 for col>=1000
__global__ void k_wconv(const float* __restrict__ W, u16* __restrict__ wb) {
  const int o = blockIdx.x * blockDim.x + threadIdx.x;   // 524288 total
  const int i = o & 7, kg = (o >> 3) & 3, col = (o >> 5) & 1023, kc = o >> 15;
  const int k = kc * 32 + kg * 8 + i;
  float v = (col < NCLS) ? W[(size_t)k * NCLS + col] : 0.f;
  wb[o] = f2bf(v);
}

// ---------------- finalize centers + |center|^2 ----------------
__global__ void k_centers(const float* __restrict__ sums, const int* __restrict__ counts,
                          const float* __restrict__ cen_in, float* __restrict__ cen,
                          float* __restrict__ sq) {
  __shared__ float red[2];
  const int c = blockIdx.x;     // 0..1023
  const int t = threadIdx.x;    // 0..127
  float4 v = make_float4(0.f, 0.f, 0.f, 0.f);
  if (c < NCLS) {
    const int cnt = counts[c];
    if (cnt > 0) {
      const float inv = 1.f / (float)cnt;
      float4 s = *(const float4*)(sums + (size_t)c * HID + t * 4);
      v = make_float4(s.x * inv, s.y * inv, s.z * inv, s.w * inv);
    } else {
      v = *(const float4*)(cen_in + (size_t)c * HID + t * 4);
    }
  }
  *(float4*)(cen + (size_t)c * HID + t * 4) = v;
  float p = v.x * v.x + v.y * v.y + v.z * v.z + v.w * v.w;
  #pragma unroll
  for (int s = 32; s; s >>= 1) p += __shfl_xor(p, s);
  if ((t & 63) == 0) red[t >> 6] = p;
  __syncthreads();
  if (t == 0) sq[c] = red[0] + red[1];
}

// ---------------- separation: Gram + exp-sum ----------------
__global__ void k_sep(const float* __restrict__ cen, const float* __restrict__ sq,
                      double* __restrict__ accum) {
  __shared__ float As[16][64];
  __shared__ float Bs[16][64];
  __shared__ float red[4];
  const int bi = blockIdx.x >> 4, bj = blockIdx.x & 15;
  const int tx = threadIdx.x & 15, ty = threadIdx.x >> 4;
  const int lrow = threadIdx.x & 63, lkq = threadIdx.x >> 6;
  float acc[4][4] = {};
  for (int k0 = 0; k0 < HID; k0 += 16) {
    __syncthreads();
    float4 a = *(const float4*)(cen + (size_t)(bi * 64 + lrow) * HID + k0 + lkq * 4);
    float4 b = *(const float4*)(cen + (size_t)(bj * 64 + lrow) * HID + k0 + lkq * 4);
    As[lkq*4+0][lrow] = a.x; As[lkq*4+1][lrow] = a.y; As[lkq*4+2][lrow] = a.z; As[lkq*4+3][lrow] = a.w;
    Bs[lkq*4+0][lrow] = b.x; Bs[lkq*4+1][lrow] = b.y; Bs[lkq*4+2][lrow] = b.z; Bs[lkq*4+3][lrow] = b.w;
    __syncthreads();
    #pragma unroll
    for (int k = 0; k < 16; ++k) {
      float4 av = *(const float4*)&As[k][ty * 4];
      float4 bv = *(const float4*)&Bs[k][tx * 4];
      float ar[4] = {av.x, av.y, av.z, av.w};
      float br[4] = {bv.x, bv.y, bv.z, bv.w};
      #pragma unroll
      for (int r = 0; r < 4; ++r)
        #pragma unroll
        for (int s = 0; s < 4; ++s)
          acc[r][s] = fmaf(ar[r], br[s], acc[r][s]);
    }
  }
  float part = 0.f;
  #pragma unroll
  for (int r = 0; r < 4; ++r) {
    const int i = bi * 64 + ty * 4 + r;
    #pragma unroll
    for (int s = 0; s < 4; ++s) {
      const int j = bj * 64 + tx * 4 + s;
      if (i < NCLS && j < NCLS) {
        float d2 = fmaxf(sq[i] + sq[j] - 2.f * acc[r][s], 0.f);
        float dist = sqrtf(d2);
        part += __expf((i == j ? 1.f : 0.f) - dist);
      }
    }
  }
  #pragma unroll
  for (int s = 32; s; s >>= 1) part += __shfl_xor(part, s);
  if ((threadIdx.x & 63) == 0) red[threadIdx.x >> 6] = part;
  __syncthreads();
  if (threadIdx.x == 0)
    atomicAdd(accum + 2, (double)(red[0] + red[1] + red[2] + red[3]));
}

// ---------------- stab GEMM (bf16 MFMA) + fused center loss ----------------
// BM=64 rows/block, BN=1024 (all cols), 8 waves each owning 128 cols, BK=32.
__global__ __launch_bounds__(512, 2)
void k_stab(const float* __restrict__ cls, const float* __restrict__ noise,
            const float* __restrict__ logits, const int* __restrict__ labels,
            const float* __restrict__ bias, const float* __restrict__ cen,
            const u16* __restrict__ wb, double* __restrict__ accum) {
  __shared__ u16 As[64 * 40];          // 64 rows x 32 k, padded stride 40 (2-way banks)
  __shared__ float red[16];
  const int lane = threadIdx.x & 63;
  const int w = threadIdx.x >> 6;
  const int row0 = blockIdx.x * 64;

  const int srow = threadIdx.x >> 3;        // staging row 0..63
  const int skq  = (threadIdx.x & 7) * 4;   // staging k offset
  const int grow = row0 + srow;
  const int lab  = labels[grow];
  const float4* clsp = (const float4*)(cls   + (size_t)grow * HID);
  const float4* noip = (const float4*)(noise + (size_t)grow * HID);
  const float4* cenp = (const float4*)(cen   + (size_t)lab  * HID);
  const int l15 = lane & 15, lkg = lane >> 4;

  f32x4 acc[4][8] = {};
  float cpart = 0.f;

  for (int kc = 0; kc < 16; ++kc) {
    __syncthreads();
    const int fidx = kc * 8 + (skq >> 2);
    float4 a = clsp[fidx];
    float4 n = noip[fidx];
    float4 c = cenp[fidx];
    float x0 = fmaf(0.1f, n.x, a.x);
    float x1 = fmaf(0.1f, n.y, a.y);
    float x2 = fmaf(0.1f, n.z, a.z);
    float x3 = fmaf(0.1f, n.w, a.w);
    float d0 = a.x - c.x, d1 = a.y - c.y, d2 = a.z - c.z, d3 = a.w - c.w;
    cpart += d0 * d0 + d1 * d1 + d2 * d2 + d3 * d3;
    u32 p0 = (u32)f2bf(x0) | ((u32)f2bf(x1) << 16);
    u32 p1 = (u32)f2bf(x2) | ((u32)f2bf(x3) << 16);
    *(uint2*)&As[srow * 40 + skq] = make_uint2(p0, p1);
    __syncthreads();

    bf16x8 af[4];
    #pragma unroll
    for (int rt = 0; rt < 4; ++rt)
      af[rt] = *(const bf16x8*)&As[(rt * 16 + l15) * 40 + lkg * 8];
    const u16* bbase = wb + (size_t)kc * 32768 + (w * 128 + l15) * 32 + lkg * 8;
    #pragma unroll
    for (int ct = 0; ct < 8; ++ct) {
      bf16x8 bfrag = *(const bf16x8*)(bbase + ct * 16 * 32);
      #pragma unroll
      for (int rt = 0; rt < 4; ++rt)
        acc[rt][ct] = __builtin_amdgcn_mfma_f32_16x16x32_bf16(af[rt], bfrag, acc[rt][ct], 0, 0, 0);
    }
  }

  // epilogue: diff^2 vs logits (C layout: col = lane&15, row = (lane>>4)*4 + reg)
  float spart = 0.f;
  #pragma unroll
  for (int ct = 0; ct < 8; ++ct) {
    const int col = w * 128 + ct * 16 + l15;
    if (col < NCLS) {
      const float bc = bias[col];
      #pragma unroll
      for (int rt = 0; rt < 4; ++rt) {
        const int rbase = row0 + rt * 16 + lkg * 4;
        #pragma unroll
        for (int r = 0; r < 4; ++r) {
          float d = acc[rt][ct][r] + bc - logits[(size_t)(rbase + r) * NCLS + col];
          spart += d * d;
        }
      }
    }
  }
  #pragma unroll
  for (int s = 32; s; s >>= 1) { spart += __shfl_xor(spart, s); cpart += __shfl_xor(cpart, s); }
  if (lane == 0) { red[w] = spart; red[8 + w] = cpart; }
  __syncthreads();
  if (threadIdx.x == 0) {
    float st = 0.f, ce = 0.f;
    #pragma unroll
    for (int i = 0; i < 8; ++i) { st += red[i]; ce += red[8 + i]; }
    atomicAdd(accum + 0, (double)st);
    atomicAdd(accum + 1, (double)ce);
  }
}

// ---------------- brier: rowwise softmax ----------------
__global__ void k_brier(const float* __restrict__ logits, const int* __restrict__ labels,
                        double* __restrict__ accum) {
  const int lane = threadIdx.x & 63;
  const int wid = (blockIdx.x * blockDim.x + threadIdx.x) >> 6;
  const int nw = (gridDim.x * blockDim.x) >> 6;
  float part = 0.f;
  for (int row = wid; row < BATCH; row += nw) {
    const float4* lr = (const float4*)(logits + (size_t)row * NCLS);
    float4 v[4];
    float m = -3.4e38f;
    #pragma unroll
    for (int it = 0; it < 4; ++it) {
      const int f = it * 64 + lane;
      if (f < 250) {
        v[it] = lr[f];
        m = fmaxf(m, fmaxf(fmaxf(v[it].x, v[it].y), fmaxf(v[it].z, v[it].w)));
      }
    }
    #pragma unroll
    for (int s = 32; s; s >>= 1) m = fmaxf(m, __shfl_xor(m, s));
    const int lab = labels[row];
    float S = 0.f, S2 = 0.f, el = 0.f;
    #pragma unroll
    for (int it = 0; it < 4; ++it) {
      const int f = it * 64 + lane;
      if (f < 250) {
        float e0 = __expf(v[it].x - m);
        float e1 = __expf(v[it].y - m);
        float e2 = __expf(v[it].z - m);
        float e3 = __expf(v[it].w - m);
        S += e0 + e1 + e2 + e3;
        S2 += e0 * e0 + e1 * e1 + e2 * e2 + e3 * e3;
        const int c0 = f * 4;
        if (c0     == lab) el = e0;
        if (c0 + 1 == lab) el = e1;
        if (c0 + 2 == lab) el = e2;
        if (c0 + 3 == lab) el = e3;
      }
    }
    #pragma unroll
    for (int s = 32; s; s >>= 1) { S += __shfl_xor(S, s); S2 += __shfl_xor(S2, s); el += __shfl_xor(el, s); }
    if (lane == 0) part += S2 / (S * S) - 2.f * el / S + 1.f;
  }
  if (lane == 0) atomicAdd(accum + 3, (double)part);
}

// ---------------- combine ----------------
__global__ void k_final(const double* __restrict__ accum, float* __restrict__ out) {
  if (threadIdx.x == 0) {
    double stab   = accum[0] / ((double)BATCH * (double)NCLS);
    double center = accum[1] / ((double)BATCH * (double)HID);
    double sep    = accum[2] - (double)NCLS;
    double brier  = accum[3] / (double)BATCH;
    double total  = 1.0 * stab + 0.1 * center + 0.01 * sep + 1.0 * brier;
    out[0] = (float)total;
    out[1] = (float)stab;
    out[2] = (float)center;
    out[3] = (float)sep;
    out[4] = (float)brier;
  }
}

extern "C" void kernel_launch(void* const* d_in, const int* in_sizes, int n_in,
                              void* d_out, int out_size, void* d_ws, size_t ws_size,
                              hipStream_t stream) {
  const float* cls    = (const float*)d_in[0];
  const float* logits = (const float*)d_in[1];
  const int*   labels = (const int*)d_in[2];
  const float* W      = (const float*)d_in[3];
  const float* bias   = (const float*)d_in[4];
  const float* noise  = (const float*)d_in[5];
  const float* cen_in = (const float*)d_in[6];
  float* out = (float*)d_out;
  char* ws = (char*)d_ws;
  if (ws_size < (size_t)WS_END) return;  // fail visibly (out stays poisoned)

  int*    counts = (int*)(ws + 0);
  double* accum  = (double*)(ws + 4096);
  float*  sq     = (float*)(ws + 8192);
  float*  sums   = (float*)(ws + 16384);
  float*  cen    = (float*)(ws + 2113536);
  u16*    wb     = (u16*)(ws + 4210688);

  hipMemsetAsync(ws, 0, 2113536, stream);   // zero counts, accum, sq, sums
  hipLaunchKernelGGL(k_count_sum, dim3(1024), dim3(256), 0, stream, cls, labels, sums, counts);
  hipLaunchKernelGGL(k_wconv,     dim3(2048), dim3(256), 0, stream, W, wb);
  hipLaunchKernelGGL(k_centers,   dim3(1024), dim3(128), 0, stream, sums, counts, cen_in, cen, sq);
  hipLaunchKernelGGL(k_sep,       dim3(256),  dim3(256), 0, stream, cen, sq, accum);
  hipLaunchKernelGGL(k_stab,      dim3(1024), dim3(512), 0, stream, cls, noise, logits, labels, bias, cen, wb, accum);
  hipLaunchKernelGGL(k_brier,     dim3(1024), dim3(256), 0, stream, logits, labels, accum);
  hipLaunchKernelGGL(k_final,     dim3(1),    dim3(64),  0, stream, accum, out);
}

// Round 2
// 518.201 us; speedup vs baseline: 1.7478x; 1.7478x over previous
//
#include <hip/hip_runtime.h>

#define BATCH 65536
#define HID   512
#define NCLS  1000
#define NCLSP 1024

typedef short bf16x8 __attribute__((ext_vector_type(8)));
typedef float f32x4 __attribute__((ext_vector_type(4)));
typedef unsigned short u16;
typedef unsigned int u32;

__device__ __forceinline__ u16 f2bf(float f) {
  u32 u = __float_as_uint(f);
  u += 0x7fffu + ((u >> 16) & 1u);
  return (u16)(u >> 16);
}

// ---------------- ws layout ----------------
// counts  int[1024]        @ 0
// accum   double[8]        @ 4096   (0 stab, 1 center, 2 sep, 3 brier)
// sq      float[1024]      @ 8192
// offsets int[1024]        @ 12288  (after k_scatter: segment END)
// order   int[65536]       @ 16384
// centers float[1024*512]  @ 278528
// WbFrag  u16[16*1024*32]  @ 2375680  (frag-linear bf16 W)
#define WS_END 3424256

// ---------------- label histogram ----------------
__global__ void k_hist(const int* __restrict__ labels, int* __restrict__ counts) {
  const int i = blockIdx.x * blockDim.x + threadIdx.x;
  if (i < BATCH) atomicAdd(counts + labels[i], 1);
}

// ---------------- exclusive prefix sum over 1024 bins (1 block) ----------------
__global__ void k_scan(const int* __restrict__ counts, int* __restrict__ offsets) {
  __shared__ int tmp[1024];
  const int t = threadIdx.x;
  const int v = counts[t];
  tmp[t] = v;
  __syncthreads();
  for (int d = 1; d < 1024; d <<= 1) {
    int u = (t >= d) ? tmp[t - d] : 0;
    __syncthreads();
    tmp[t] += u;
    __syncthreads();
  }
  offsets[t] = tmp[t] - v;   // exclusive
}

// ---------------- scatter row indices into class-sorted order ----------------
__global__ void k_scatter(const int* __restrict__ labels, int* __restrict__ offsets,
                          int* __restrict__ order) {
  const int i = blockIdx.x * blockDim.x + threadIdx.x;
  if (i < BATCH) {
    const int pos = atomicAdd(offsets + labels[i], 1);
    order[pos] = i;
  }
}

// ---------------- segmented mean -> centers, plus |center|^2 ----------------
__global__ void k_segsum(const float* __restrict__ cls, const int* __restrict__ order,
                         const int* __restrict__ offsets, const int* __restrict__ counts,
                         const float* __restrict__ cen_in, float* __restrict__ cen,
                         float* __restrict__ sq) {
  __shared__ float red[8];
  const int c = blockIdx.x;     // 0..1023
  const int t = threadIdx.x;    // 0..511 (one column each)
  const int cnt = counts[c];
  const int end = offsets[c];   // after scatter, offsets[c] == segment end
  const int start = end - cnt;
  float v;
  if (cnt > 0) {
    float s0 = 0.f, s1 = 0.f, s2 = 0.f, s3 = 0.f;
    int i = start;
    for (; i + 4 <= end; i += 4) {
      const int r0 = order[i], r1 = order[i + 1], r2 = order[i + 2], r3 = order[i + 3];
      s0 += cls[(size_t)r0 * HID + t];
      s1 += cls[(size_t)r1 * HID + t];
      s2 += cls[(size_t)r2 * HID + t];
      s3 += cls[(size_t)r3 * HID + t];
    }
    for (; i < end; ++i) s0 += cls[(size_t)order[i] * HID + t];
    v = ((s0 + s1) + (s2 + s3)) / (float)cnt;
  } else {
    v = (c < NCLS) ? cen_in[(size_t)c * HID + t] : 0.f;
  }
  cen[(size_t)c * HID + t] = v;
  float p = v * v;
  #pragma unroll
  for (int s = 32; s; s >>= 1) p += __shfl_xor(p, s);
  if ((t & 63) == 0) red[t >> 6] = p;
  __syncthreads();
  if (t == 0) {
    float acc = 0.f;
    #pragma unroll
    for (int i = 0; i < 8; ++i) acc += red[i];
    sq[c] = acc;
  }
}

// ---------------- W f32 -> fragment-linear bf16 ----------------
// WbFrag[((kc*1024 + col)*4 + kg)*8 + i] = W[kc*32 + kg*8 + i][col], 0 for col>=1000
__global__ void k_wconv(const float* __restrict__ W, u16* __restrict__ wb) {
  const int o = blockIdx.x * blockDim.x + threadIdx.x;   // 524288 total
  const int i = o & 7, kg = (o >> 3) & 3, col = (o >> 5) & 1023, kc = o >> 15;
  const int k = kc * 32 + kg * 8 + i;
  float v = (col < NCLS) ? W[(size_t)k * NCLS + col] : 0.f;
  wb[o] = f2bf(v);
}

// ---------------- separation: Gram + exp-sum ----------------
__global__ void k_sep(const float* __restrict__ cen, const float* __restrict__ sq,
                      double* __restrict__ accum) {
  __shared__ float As[16][64];
  __shared__ float Bs[16][64];
  __shared__ float red[4];
  const int bi = blockIdx.x >> 4, bj = blockIdx.x & 15;
  const int tx = threadIdx.x & 15, ty = threadIdx.x >> 4;
  const int lrow = threadIdx.x & 63, lkq = threadIdx.x >> 6;
  float acc[4][4] = {};
  for (int k0 = 0; k0 < HID; k0 += 16) {
    __syncthreads();
    float4 a = *(const float4*)(cen + (size_t)(bi * 64 + lrow) * HID + k0 + lkq * 4);
    float4 b = *(const float4*)(cen + (size_t)(bj * 64 + lrow) * HID + k0 + lkq * 4);
    As[lkq*4+0][lrow] = a.x; As[lkq*4+1][lrow] = a.y; As[lkq*4+2][lrow] = a.z; As[lkq*4+3][lrow] = a.w;
    Bs[lkq*4+0][lrow] = b.x; Bs[lkq*4+1][lrow] = b.y; Bs[lkq*4+2][lrow] = b.z; Bs[lkq*4+3][lrow] = b.w;
    __syncthreads();
    #pragma unroll
    for (int k = 0; k < 16; ++k) {
      float4 av = *(const float4*)&As[k][ty * 4];
      float4 bv = *(const float4*)&Bs[k][tx * 4];
      float ar[4] = {av.x, av.y, av.z, av.w};
      float br[4] = {bv.x, bv.y, bv.z, bv.w};
      #pragma unroll
      for (int r = 0; r < 4; ++r)
        #pragma unroll
        for (int s = 0; s < 4; ++s)
          acc[r][s] = fmaf(ar[r], br[s], acc[r][s]);
    }
  }
  float part = 0.f;
  #pragma unroll
  for (int r = 0; r < 4; ++r) {
    const int i = bi * 64 + ty * 4 + r;
    #pragma unroll
    for (int s = 0; s < 4; ++s) {
      const int j = bj * 64 + tx * 4 + s;
      if (i < NCLS && j < NCLS) {
        float d2 = fmaxf(sq[i] + sq[j] - 2.f * acc[r][s], 0.f);
        float dist = sqrtf(d2);
        part += __expf((i == j ? 1.f : 0.f) - dist);
      }
    }
  }
  #pragma unroll
  for (int s = 32; s; s >>= 1) part += __shfl_xor(part, s);
  if ((threadIdx.x & 63) == 0) red[threadIdx.x >> 6] = part;
  __syncthreads();
  if (threadIdx.x == 0)
    atomicAdd(accum + 2, (double)(red[0] + red[1] + red[2] + red[3]));
}

// ---------------- stab GEMM (bf16 MFMA) + fused center loss ----------------
// BM=64 rows/block, BN=1024 (all cols), 8 waves each owning 128 cols, BK=32.
__global__ __launch_bounds__(512, 2)
void k_stab(const float* __restrict__ cls, const float* __restrict__ noise,
            const float* __restrict__ logits, const int* __restrict__ labels,
            const float* __restrict__ bias, const float* __restrict__ cen,
            const u16* __restrict__ wb, double* __restrict__ accum) {
  __shared__ u16 As[64 * 40];          // 64 rows x 32 k, padded stride 40 (2-way banks)
  __shared__ float red[16];
  const int lane = threadIdx.x & 63;
  const int w = threadIdx.x >> 6;
  const int row0 = blockIdx.x * 64;

  const int srow = threadIdx.x >> 3;        // staging row 0..63
  const int skq  = (threadIdx.x & 7) * 4;   // staging k offset
  const int grow = row0 + srow;
  const int lab  = labels[grow];
  const float4* clsp = (const float4*)(cls   + (size_t)grow * HID);
  const float4* noip = (const float4*)(noise + (size_t)grow * HID);
  const float4* cenp = (const float4*)(cen   + (size_t)lab  * HID);
  const int l15 = lane & 15, lkg = lane >> 4;

  f32x4 acc[4][8] = {};
  float cpart = 0.f;

  for (int kc = 0; kc < 16; ++kc) {
    __syncthreads();
    const int fidx = kc * 8 + (skq >> 2);
    float4 a = clsp[fidx];
    float4 n = noip[fidx];
    float4 c = cenp[fidx];
    float x0 = fmaf(0.1f, n.x, a.x);
    float x1 = fmaf(0.1f, n.y, a.y);
    float x2 = fmaf(0.1f, n.z, a.z);
    float x3 = fmaf(0.1f, n.w, a.w);
    float d0 = a.x - c.x, d1 = a.y - c.y, d2 = a.z - c.z, d3 = a.w - c.w;
    cpart += d0 * d0 + d1 * d1 + d2 * d2 + d3 * d3;
    u32 p0 = (u32)f2bf(x0) | ((u32)f2bf(x1) << 16);
    u32 p1 = (u32)f2bf(x2) | ((u32)f2bf(x3) << 16);
    *(uint2*)&As[srow * 40 + skq] = make_uint2(p0, p1);
    __syncthreads();

    bf16x8 af[4];
    #pragma unroll
    for (int rt = 0; rt < 4; ++rt)
      af[rt] = *(const bf16x8*)&As[(rt * 16 + l15) * 40 + lkg * 8];
    const u16* bbase = wb + (size_t)kc * 32768 + (w * 128 + l15) * 32 + lkg * 8;
    #pragma unroll
    for (int ct = 0; ct < 8; ++ct) {
      bf16x8 bfrag = *(const bf16x8*)(bbase + ct * 16 * 32);
      #pragma unroll
      for (int rt = 0; rt < 4; ++rt)
        acc[rt][ct] = __builtin_amdgcn_mfma_f32_16x16x32_bf16(af[rt], bfrag, acc[rt][ct], 0, 0, 0);
    }
  }

  // epilogue: diff^2 vs logits (C layout: col = lane&15, row = (lane>>4)*4 + reg)
  float spart = 0.f;
  #pragma unroll
  for (int ct = 0; ct < 8; ++ct) {
    const int col = w * 128 + ct * 16 + l15;
    if (col < NCLS) {
      const float bc = bias[col];
      #pragma unroll
      for (int rt = 0; rt < 4; ++rt) {
        const int rbase = row0 + rt * 16 + lkg * 4;
        #pragma unroll
        for (int r = 0; r < 4; ++r) {
          float d = acc[rt][ct][r] + bc - logits[(size_t)(rbase + r) * NCLS + col];
          spart += d * d;
        }
      }
    }
  }
  #pragma unroll
  for (int s = 32; s; s >>= 1) { spart += __shfl_xor(spart, s); cpart += __shfl_xor(cpart, s); }
  if (lane == 0) { red[w] = spart; red[8 + w] = cpart; }
  __syncthreads();
  if (threadIdx.x == 0) {
    float st = 0.f, ce = 0.f;
    #pragma unroll
    for (int i = 0; i < 8; ++i) { st += red[i]; ce += red[8 + i]; }
    atomicAdd(accum + 0, (double)st);
    atomicAdd(accum + 1, (double)ce);
  }
}

// ---------------- brier: rowwise softmax ----------------
__global__ void k_brier(const float* __restrict__ logits, const int* __restrict__ labels,
                        double* __restrict__ accum) {
  const int lane = threadIdx.x & 63;
  const int wid = (blockIdx.x * blockDim.x + threadIdx.x) >> 6;
  const int nw = (gridDim.x * blockDim.x) >> 6;
  float part = 0.f;
  for (int row = wid; row < BATCH; row += nw) {
    const float4* lr = (const float4*)(logits + (size_t)row * NCLS);
    float4 v[4];
    float m = -3.4e38f;
    #pragma unroll
    for (int it = 0; it < 4; ++it) {
      const int f = it * 64 + lane;
      if (f < 250) {
        v[it] = lr[f];
        m = fmaxf(m, fmaxf(fmaxf(v[it].x, v[it].y), fmaxf(v[it].z, v[it].w)));
      }
    }
    #pragma unroll
    for (int s = 32; s; s >>= 1) m = fmaxf(m, __shfl_xor(m, s));
    const int lab = labels[row];
    float S = 0.f, S2 = 0.f, el = 0.f;
    #pragma unroll
    for (int it = 0; it < 4; ++it) {
      const int f = it * 64 + lane;
      if (f < 250) {
        float e0 = __expf(v[it].x - m);
        float e1 = __expf(v[it].y - m);
        float e2 = __expf(v[it].z - m);
        float e3 = __expf(v[it].w - m);
        S += e0 + e1 + e2 + e3;
        S2 += e0 * e0 + e1 * e1 + e2 * e2 + e3 * e3;
        const int c0 = f * 4;
        if (c0     == lab) el = e0;
        if (c0 + 1 == lab) el = e1;
        if (c0 + 2 == lab) el = e2;
        if (c0 + 3 == lab) el = e3;
      }
    }
    #pragma unroll
    for (int s = 32; s; s >>= 1) { S += __shfl_xor(S, s); S2 += __shfl_xor(S2, s); el += __shfl_xor(el, s); }
    if (lane == 0) part += S2 / (S * S) - 2.f * el / S + 1.f;
  }
  if (lane == 0) atomicAdd(accum + 3, (double)part);
}

// ---------------- combine ----------------
__global__ void k_final(const double* __restrict__ accum, float* __restrict__ out) {
  if (threadIdx.x == 0) {
    double stab   = accum[0] / ((double)BATCH * (double)NCLS);
    double center = accum[1] / ((double)BATCH * (double)HID);
    double sep    = accum[2] - (double)NCLS;
    double brier  = accum[3] / (double)BATCH;
    double total  = 1.0 * stab + 0.1 * center + 0.01 * sep + 1.0 * brier;
    out[0] = (float)total;
    out[1] = (float)stab;
    out[2] = (float)center;
    out[3] = (float)sep;
    out[4] = (float)brier;
  }
}

extern "C" void kernel_launch(void* const* d_in, const int* in_sizes, int n_in,
                              void* d_out, int out_size, void* d_ws, size_t ws_size,
                              hipStream_t stream) {
  const float* cls    = (const float*)d_in[0];
  const float* logits = (const float*)d_in[1];
  const int*   labels = (const int*)d_in[2];
  const float* W      = (const float*)d_in[3];
  const float* bias   = (const float*)d_in[4];
  const float* noise  = (const float*)d_in[5];
  const float* cen_in = (const float*)d_in[6];
  float* out = (float*)d_out;
  char* ws = (char*)d_ws;
  if (ws_size < (size_t)WS_END) return;  // fail visibly (out stays poisoned)

  int*    counts  = (int*)(ws + 0);
  double* accum   = (double*)(ws + 4096);
  float*  sq      = (float*)(ws + 8192);
  int*    offsets = (int*)(ws + 12288);
  int*    order   = (int*)(ws + 16384);
  float*  cen     = (float*)(ws + 278528);
  u16*    wb      = (u16*)(ws + 2375680);

  hipMemsetAsync(ws, 0, 4160, stream);   // zero counts + accum
  hipLaunchKernelGGL(k_hist,    dim3(256),  dim3(256), 0, stream, labels, counts);
  hipLaunchKernelGGL(k_wconv,   dim3(2048), dim3(256), 0, stream, W, wb);
  hipLaunchKernelGGL(k_scan,    dim3(1),    dim3(1024),0, stream, counts, offsets);
  hipLaunchKernelGGL(k_scatter, dim3(256),  dim3(256), 0, stream, labels, offsets, order);
  hipLaunchKernelGGL(k_segsum,  dim3(1024), dim3(512), 0, stream, cls, order, offsets, counts, cen_in, cen, sq);
  hipLaunchKernelGGL(k_sep,     dim3(256),  dim3(256), 0, stream, cen, sq, accum);
  hipLaunchKernelGGL(k_stab,    dim3(1024), dim3(512), 0, stream, cls, noise, logits, labels, bias, cen, wb, accum);
  hipLaunchKernelGGL(k_brier,   dim3(1024), dim3(256), 0, stream, logits, labels, accum);
  hipLaunchKernelGGL(k_final,   dim3(1),    dim3(64),  0, stream, accum, out);
}